// Round 3
// baseline (3485.310 us; speedup 1.0000x reference)
//
#include <hip/hip_runtime.h>
#include <hip/hip_bf16.h>

typedef __hip_bfloat16 bf16;

#define QL   2048
#define KLEN 2048
#define BATCH 2
#define EMB  1024
#define NH   16
#define HD   64
#define SPE  4095   // 2*KLEN - 1 pe rows (slice starts at pe row 1)

// ---------------------------------------------------------------------------
// dtype-agnostic load (inputs are f32 per contract; detection keeps us safe
// either way). Index is in ELEMENTS.
// ---------------------------------------------------------------------------
__device__ __forceinline__ float ldf(const void* __restrict__ p, size_t i, int f32) {
    return f32 ? ((const float*)p)[i] : __bfloat162float(((const bf16*)p)[i]);
}

// Probe first 256 u16 words as bf16. Genuine bf16 activations never have
// |x| >= 2^11; f32 mantissa halves have random exponents (~46% exceed).
__device__ int detect_f32(const void* __restrict__ p) {
    const unsigned short* u = (const unsigned short*)p;
    int bad = 0;
    for (int i = 0; i < 256; i++) {
        int e = (u[i] >> 7) & 0xFF;
        if (e >= 0x8A) bad++;   // |x| >= 2048, or NaN/Inf
    }
    return bad >= 8;
}

// ---------------------------------------------------------------------------
// GEMM: C[M,1024] = A[M,1024] @ W[1024,1024]^T  (torch Linear), fp32 accum.
// MODE 0: query proj -> qc = q+content_bias, qp = q+pos_bias, [B][H][QL][HD]
// MODE 1: key/value proj -> [B][H][KLEN][HD]
// MODE 2: pe proj (elemOff=EMB skips pe row 0) -> [H][SPE][HD]
// MODE 3: final out proj -> row-major [M][1024] FLOAT (d_out); A is ws bf16.
// ---------------------------------------------------------------------------
template<int MODE>
__global__ __launch_bounds__(256) void gemm_bt(
    const void* __restrict__ A, const void* __restrict__ W,
    bf16* __restrict__ out0, bf16* __restrict__ out1,
    float* __restrict__ outf,
    const void* __restrict__ bias0, const void* __restrict__ bias1,
    int M, int elemOff)
{
    __shared__ float As[16][65];
    __shared__ float Ws[16][65];
    __shared__ int sflag, wflag;
    const int t  = threadIdx.x;
    const int tx = t & 15, ty = t >> 4;
    const int m0 = blockIdx.x * 64;
    const int n0 = blockIdx.y * 64;

    if (t == 0) {
        sflag = (MODE == 3) ? 0 : detect_f32(A);   // MODE 3 A is our bf16 ws
        wflag = detect_f32(W);
    }
    __syncthreads();
    const int f32 = sflag;
    const int wf32 = wflag;

    float acc[4][4] = {};

    for (int k0 = 0; k0 < 1024; k0 += 16) {
#pragma unroll
        for (int i = 0; i < 4; i++) {
            int id  = i * 256 + t;
            int kk  = id & 15, row = id >> 4;
            int gm  = m0 + row;
            As[kk][row] = (gm < M) ? ldf(A, (size_t)elemOff + (size_t)gm * 1024 + k0 + kk, f32) : 0.0f;
            Ws[kk][row] = ldf(W, (size_t)(n0 + row) * 1024 + k0 + kk, wf32);
        }
        __syncthreads();
#pragma unroll
        for (int kk = 0; kk < 16; kk++) {
            float av[4], wv[4];
#pragma unroll
            for (int i = 0; i < 4; i++) av[i] = As[kk][ty * 4 + i];
#pragma unroll
            for (int j = 0; j < 4; j++) wv[j] = Ws[kk][tx * 4 + j];
#pragma unroll
            for (int i = 0; i < 4; i++)
#pragma unroll
                for (int j = 0; j < 4; j++)
                    acc[i][j] += av[i] * wv[j];
        }
        __syncthreads();
    }

#pragma unroll
    for (int i = 0; i < 4; i++) {
        int r = m0 + ty * 4 + i;
        if (r >= M) continue;
#pragma unroll
        for (int j = 0; j < 4; j++) {
            int c = n0 + tx * 4 + j;
            float v = acc[i][j];
            if constexpr (MODE == 0) {
                int l = r >> 1, b = r & 1;
                int h = c >> 6, d = c & 63;
                size_t idx = ((size_t)(b * NH + h) * QL + l) * HD + d;
                out0[idx] = (bf16)(v + ldf(bias0, c, f32));
                out1[idx] = (bf16)(v + ldf(bias1, c, f32));
            } else if constexpr (MODE == 1) {
                int l = r >> 1, b = r & 1;
                int h = c >> 6, d = c & 63;
                size_t idx = ((size_t)(b * NH + h) * KLEN + l) * HD + d;
                out0[idx] = (bf16)v;
            } else if constexpr (MODE == 2) {
                int h = c >> 6, d = c & 63;
                size_t idx = ((size_t)h * SPE + r) * HD + d;
                out0[idx] = (bf16)v;
            } else {
                outf[(size_t)r * 1024 + c] = v;   // f32 output per contract
            }
        }
    }
}

// ---------------------------------------------------------------------------
// Flash-style causal attention with TXL relative positions.
// score[q,k] = ((q+cb)·k_vec + (q+pb)·kpos[k - q + 2047]) * 0.125, k <= q.
// One block: (b, h, 32 q-rows); k-tiles of 32 with online softmax.
// ---------------------------------------------------------------------------
#define BQ 32
#define BK 32
#define NEG_INF (-1.0e30f)

__global__ __launch_bounds__(256) void attn_kernel(
    const bf16* __restrict__ qc_g, const bf16* __restrict__ qp_g,
    const bf16* __restrict__ k_g,  const bf16* __restrict__ v_g,
    const bf16* __restrict__ kpos_g, bf16* __restrict__ ao)
{
    const int q0 = blockIdx.x * BQ;
    const int h  = blockIdx.y;
    const int b  = blockIdx.z;

    const bf16* qc_bh  = qc_g + ((size_t)(b * NH + h) * QL) * HD;
    const bf16* qp_bh  = qp_g + ((size_t)(b * NH + h) * QL) * HD;
    const bf16* k_bh   = k_g  + ((size_t)(b * NH + h) * KLEN) * HD;
    const bf16* v_bh   = v_g  + ((size_t)(b * NH + h) * KLEN) * HD;
    const bf16* kpos_h = kpos_g + (size_t)h * SPE * HD;

    __shared__ float Qc[BQ][65], Qp[BQ][65];
    __shared__ float Kt[BK][65], Vt[BK][65];
    __shared__ float Kp[63][65];
    __shared__ float Sm[BQ][BK + 1];
    __shared__ float mrow[BQ], lrow[BQ], arow[BQ];

    const int t = threadIdx.x;

#pragma unroll
    for (int i = 0; i < 8; i++) {
        int id = i * 256 + t;
        int row = id >> 6, d = id & 63;
        Qc[row][d] = (float)qc_bh[(size_t)(q0 + row) * HD + d];
        Qp[row][d] = (float)qp_bh[(size_t)(q0 + row) * HD + d];
    }
    if (t < BQ) { mrow[t] = NEG_INF; lrow[t] = 0.0f; }
    __syncthreads();

    const int qi = t >> 3;          // 0..31  (owned q row)
    const int dg = (t & 7) * 8;     // d-range base for O accumulation
    const int kg = (t & 7) * 4;     // kj base for S compute
    float Oacc[8] = {};

    const int ktiles = blockIdx.x + 1;   // causal: k0 <= q0
    for (int kt = 0; kt < ktiles; kt++) {
        const int k0 = kt * BK;
        const int s0 = k0 - q0 + 2016;   // kpos row base (always >= 0)

#pragma unroll
        for (int i = 0; i < 8; i++) {
            int id = i * 256 + t;
            int row = id >> 6, d = id & 63;
            Kt[row][d] = (float)k_bh[(size_t)(k0 + row) * HD + d];
            Vt[row][d] = (float)v_bh[(size_t)(k0 + row) * HD + d];
        }
#pragma unroll
        for (int i = 0; i < 16; i++) {
            int id = i * 256 + t;          // need 63*64 = 4032 of 4096
            int row = id >> 6, d = id & 63;
            if (row < 63) Kp[row][d] = (float)kpos_h[(size_t)(s0 + row) * HD + d];
        }
        __syncthreads();

        // ---- scores: 4 elements per thread ----
        float s_acc[4] = {};
        for (int d = 0; d < 64; d++) {
            float qcv = Qc[qi][d];
            float qpv = Qp[qi][d];
#pragma unroll
            for (int j = 0; j < 4; j++) {
                int kj = kg + j;
                s_acc[j] += qcv * Kt[kj][d] + qpv * Kp[kj - qi + 31][d];
            }
        }
#pragma unroll
        for (int j = 0; j < 4; j++) {
            int kj = kg + j;
            float sv = s_acc[j] * 0.125f;
            if (k0 + kj > q0 + qi) sv = NEG_INF;   // causal mask
            Sm[qi][kj] = sv;
        }
        __syncthreads();

        // ---- online softmax (one thread per row) ----
        if (t < BQ) {
            float mold = mrow[t];
            float mx = mold;
            for (int kj = 0; kj < BK; kj++) mx = fmaxf(mx, Sm[t][kj]);
            float alpha = __expf(mold - mx);
            float lsum = 0.0f;
            for (int kj = 0; kj < BK; kj++) {
                float p = __expf(Sm[t][kj] - mx);
                Sm[t][kj] = p;
                lsum += p;
            }
            lrow[t] = lrow[t] * alpha + lsum;
            mrow[t] = mx;
            arow[t] = alpha;
        }
        __syncthreads();

        // ---- O update ----
        float alpha = arow[qi];
#pragma unroll
        for (int j = 0; j < 8; j++) Oacc[j] *= alpha;
        for (int kj = 0; kj < BK; kj++) {
            float p = Sm[qi][kj];
#pragma unroll
            for (int j = 0; j < 8; j++) Oacc[j] += p * Vt[kj][dg + j];
        }
        __syncthreads();
    }

    const float linv = 1.0f / lrow[qi];
#pragma unroll
    for (int j = 0; j < 8; j++) {
        // attn-out layout [QL][BATCH][EMB] so final GEMM is plain row-major
        ao[(((size_t)(q0 + qi) * BATCH + b) * EMB) + h * HD + dg + j] =
            (bf16)(Oacc[j] * linv);
    }
}

// ---------------------------------------------------------------------------
extern "C" void kernel_launch(void* const* d_in, const int* in_sizes, int n_in,
                              void* d_out, int out_size, void* d_ws, size_t ws_size,
                              hipStream_t stream)
{
    const void* query = d_in[0];
    const void* key   = d_in[1];
    const void* value = d_in[2];
    const void* pe    = d_in[3];
    const void* w_q   = d_in[4];
    const void* w_k   = d_in[5];
    const void* w_v   = d_in[6];
    const void* w_kp  = d_in[7];
    const void* w_out = d_in[8];
    const void* cb    = d_in[9];
    const void* pb    = d_in[10];
    float* out = (float*)d_out;   // reference output dtype is float32

    // workspace carve-up (bf16, 4 MiB elems each slab)
    bf16* qc = (bf16*)d_ws;
    bf16* qp = qc + (size_t)4194304;
    bf16* kw = qp + (size_t)4194304;
    bf16* vw = kw + (size_t)4194304;
    bf16* kp = vw + (size_t)4194304;   // uses 16*4095*64 = 4,193,280
    bf16* ao = kp + (size_t)4194304;

    dim3 blk(256);
    // projections
    gemm_bt<0><<<dim3(64, 16), blk, 0, stream>>>(query, w_q, qc, qp, nullptr, cb, pb, QL * BATCH, 0);
    gemm_bt<1><<<dim3(64, 16), blk, 0, stream>>>(key,   w_k, kw, nullptr, nullptr, nullptr, nullptr, KLEN * BATCH, 0);
    gemm_bt<1><<<dim3(64, 16), blk, 0, stream>>>(value, w_v, vw, nullptr, nullptr, nullptr, nullptr, KLEN * BATCH, 0);
    gemm_bt<2><<<dim3(64, 16), blk, 0, stream>>>(pe, w_kp, kp, nullptr, nullptr, nullptr, nullptr, SPE, EMB);

    // attention
    attn_kernel<<<dim3(QL / BQ, NH, BATCH), blk, 0, stream>>>(qc, qp, kw, vw, kp, ao);

    // output projection (f32 out)
    gemm_bt<3><<<dim3(64, 16), blk, 0, stream>>>(ao, w_out, nullptr, nullptr, out, nullptr, nullptr, QL * BATCH, 0);
}

// Round 4
// 1701.098 us; speedup vs baseline: 2.0489x; 2.0489x over previous
//
#include <hip/hip_runtime.h>
#include <hip/hip_bf16.h>

typedef __hip_bfloat16 bf16;
typedef __attribute__((ext_vector_type(8))) short short8;
typedef __attribute__((ext_vector_type(4))) float f32x4;
typedef __attribute__((ext_vector_type(4))) unsigned int u32x4;

#define QL   2048
#define KLEN 2048
#define BATCH 2
#define EMB  1024
#define NH   16
#define HD   64
#define SPE  4095   // 2*KLEN - 1 pe rows (slice starts at pe row 1)

// ---------------------------------------------------------------------------
// dtype-agnostic load (inputs are f32; detection keeps us safe either way)
// ---------------------------------------------------------------------------
__device__ __forceinline__ float ldf(const void* __restrict__ p, size_t i, int f32) {
    return f32 ? ((const float*)p)[i] : __bfloat162float(((const bf16*)p)[i]);
}

__device__ int detect_f32(const void* __restrict__ p) {
    const unsigned short* u = (const unsigned short*)p;
    int bad = 0;
    for (int i = 0; i < 256; i++) {
        int e = (u[i] >> 7) & 0xFF;
        if (e >= 0x8A) bad++;   // |x| >= 2048, or NaN/Inf
    }
    return bad >= 8;
}

// ---------------------------------------------------------------------------
// GEMM: C[M,1024] = A[M,1024] @ W[1024,1024]^T, fp32 accum. (unchanged, passing)
// ---------------------------------------------------------------------------
template<int MODE>
__global__ __launch_bounds__(256) void gemm_bt(
    const void* __restrict__ A, const void* __restrict__ W,
    bf16* __restrict__ out0, bf16* __restrict__ out1,
    float* __restrict__ outf,
    const void* __restrict__ bias0, const void* __restrict__ bias1,
    int M, int elemOff)
{
    __shared__ float As[16][65];
    __shared__ float Ws[16][65];
    __shared__ int sflag, wflag;
    const int t  = threadIdx.x;
    const int tx = t & 15, ty = t >> 4;
    const int m0 = blockIdx.x * 64;
    const int n0 = blockIdx.y * 64;

    if (t == 0) {
        sflag = (MODE == 3) ? 0 : detect_f32(A);
        wflag = detect_f32(W);
    }
    __syncthreads();
    const int f32 = sflag;
    const int wf32 = wflag;

    float acc[4][4] = {};

    for (int k0 = 0; k0 < 1024; k0 += 16) {
#pragma unroll
        for (int i = 0; i < 4; i++) {
            int id  = i * 256 + t;
            int kk  = id & 15, row = id >> 4;
            int gm  = m0 + row;
            As[kk][row] = (gm < M) ? ldf(A, (size_t)elemOff + (size_t)gm * 1024 + k0 + kk, f32) : 0.0f;
            Ws[kk][row] = ldf(W, (size_t)(n0 + row) * 1024 + k0 + kk, wf32);
        }
        __syncthreads();
#pragma unroll
        for (int kk = 0; kk < 16; kk++) {
            float av[4], wv[4];
#pragma unroll
            for (int i = 0; i < 4; i++) av[i] = As[kk][ty * 4 + i];
#pragma unroll
            for (int j = 0; j < 4; j++) wv[j] = Ws[kk][tx * 4 + j];
#pragma unroll
            for (int i = 0; i < 4; i++)
#pragma unroll
                for (int j = 0; j < 4; j++)
                    acc[i][j] += av[i] * wv[j];
        }
        __syncthreads();
    }

#pragma unroll
    for (int i = 0; i < 4; i++) {
        int r = m0 + ty * 4 + i;
        if (r >= M) continue;
#pragma unroll
        for (int j = 0; j < 4; j++) {
            int c = n0 + tx * 4 + j;
            float v = acc[i][j];
            if constexpr (MODE == 0) {
                int l = r >> 1, b = r & 1;
                int h = c >> 6, d = c & 63;
                size_t idx = ((size_t)(b * NH + h) * QL + l) * HD + d;
                out0[idx] = (bf16)(v + ldf(bias0, c, f32));
                out1[idx] = (bf16)(v + ldf(bias1, c, f32));
            } else if constexpr (MODE == 1) {
                int l = r >> 1, b = r & 1;
                int h = c >> 6, d = c & 63;
                size_t idx = ((size_t)(b * NH + h) * KLEN + l) * HD + d;
                out0[idx] = (bf16)v;
            } else if constexpr (MODE == 2) {
                int h = c >> 6, d = c & 63;
                size_t idx = ((size_t)h * SPE + r) * HD + d;
                out0[idx] = (bf16)v;
            } else {
                outf[(size_t)r * 1024 + c] = v;
            }
        }
    }
}

// ---------------------------------------------------------------------------
// MFMA flash attention with TXL relative positions.
// Block = (b, h, 32 q-rows), 256 threads (4 waves), k-tiles of 64.
// pos band: P~[32][96] = Qp @ kpos[s0:s0+96]^T, gathered at s' = col - r + 31.
// ---------------------------------------------------------------------------
#define NEG_INF (-1.0e30f)

__global__ __launch_bounds__(256) void attn_mfma(
    const bf16* __restrict__ qc_g, const bf16* __restrict__ qp_g,
    const bf16* __restrict__ k_g,  const bf16* __restrict__ v_g,
    const bf16* __restrict__ kpos_g, bf16* __restrict__ ao)
{
    const int bx = blockIdx.x;
    const int h  = blockIdx.y;
    const int b  = blockIdx.z;
    const int q0 = bx * 32;

    const bf16* qc_bh  = qc_g + ((size_t)(b * NH + h) * QL) * HD;
    const bf16* qp_bh  = qp_g + ((size_t)(b * NH + h) * QL) * HD;
    const bf16* k_bh   = k_g  + ((size_t)(b * NH + h) * KLEN) * HD;
    const bf16* v_bh   = v_g  + ((size_t)(b * NH + h) * KLEN) * HD;
    const bf16* kpos_h = kpos_g + (size_t)h * SPE * HD;

    __shared__ __align__(16) bf16 Qc_s[32][72];
    __shared__ __align__(16) bf16 Qp_s[32][72];
    __shared__ __align__(16) bf16 K_s [64][72];
    __shared__ __align__(16) bf16 V_s [64][66];
    __shared__ __align__(16) bf16 Kp_s[96][72];
    __shared__ __align__(16) float Sc_s[32][65];
    __shared__ __align__(16) float Pt_s[32][97];
    __shared__ float arow_s[32];
    bf16* Pb = (bf16*)&Sc_s[0][0];   // [32][72] bf16 alias (after sync)

    const int t = threadIdx.x;
    const int w = t >> 6, lane = t & 63, lm = lane & 15, quad = lane >> 4;

    // ---- stage Q tiles once ----
    {
        int row = t >> 3, ch = (t & 7) * 8;
        *(u32x4*)&Qc_s[row][ch] = *(const u32x4*)&qc_bh[(size_t)(q0 + row) * HD + ch];
        *(u32x4*)&Qp_s[row][ch] = *(const u32x4*)&qp_bh[(size_t)(q0 + row) * HD + ch];
    }

    const int sr = t >> 3;            // softmax: owned row
    const int sc = (t & 7) * 8;       // softmax: col chunk
    float m_run = NEG_INF, l_run = 0.0f;

    const int mtc = w & 1;            // content/PV m-tile
    const int ntc = (w >> 1) * 2;     // content/PV n-tile base (2 tiles)
    const int mtp = w >> 1;           // pos m-tile
    const int ntp = (w & 1) * 3;      // pos n-tile base (3 tiles)

    f32x4 accO[2] = {{0,0,0,0},{0,0,0,0}};

    const int nkt = (bx >> 1) + 1;
    for (int kt = 0; kt < nkt; kt++) {
        const int k0 = kt * 64;
        const int s0 = k0 - q0 + 2016;

        // ---- stage K(64x64,str72), V(64x64,str66), Kp(96x64,str72) ----
#pragma unroll
        for (int i = 0; i < 2; i++) {
            int idx = i * 256 + t, row = idx >> 3, ch = (idx & 7) * 8;
            *(u32x4*)&K_s[row][ch] = *(const u32x4*)&k_bh[(size_t)(k0 + row) * HD + ch];
        }
#pragma unroll
        for (int i = 0; i < 8; i++) {
            int idx = i * 256 + t, row = idx >> 5, c2 = idx & 31;
            *(unsigned int*)&V_s[row][c2 * 2] =
                *(const unsigned int*)&v_bh[(size_t)(k0 + row) * HD + c2 * 2];
        }
#pragma unroll
        for (int i = 0; i < 3; i++) {
            int idx = i * 256 + t, row = idx >> 3, ch = (idx & 7) * 8;
            *(u32x4*)&Kp_s[row][ch] = *(const u32x4*)&kpos_h[(size_t)(s0 + row) * HD + ch];
        }
        __syncthreads();   // A: staging visible

        // ---- content scores S = Qc K^T ----
        {
            short8 a0 = *(const short8*)&Qc_s[mtc * 16 + lm][quad * 8];
            short8 a1 = *(const short8*)&Qc_s[mtc * 16 + lm][32 + quad * 8];
#pragma unroll
            for (int n = 0; n < 2; n++) {
                int nt = ntc + n;
                short8 b0 = *(const short8*)&K_s[nt * 16 + lm][quad * 8];
                short8 b1 = *(const short8*)&K_s[nt * 16 + lm][32 + quad * 8];
                f32x4 acc = {0, 0, 0, 0};
                acc = __builtin_amdgcn_mfma_f32_16x16x32_bf16(a0, b0, acc, 0, 0, 0);
                acc = __builtin_amdgcn_mfma_f32_16x16x32_bf16(a1, b1, acc, 0, 0, 0);
#pragma unroll
                for (int r = 0; r < 4; r++)
                    Sc_s[mtc * 16 + quad * 4 + r][nt * 16 + lm] = acc[r];
            }
        }
        // ---- pos band P~ = Qp Kp^T ----
        {
            short8 a0 = *(const short8*)&Qp_s[mtp * 16 + lm][quad * 8];
            short8 a1 = *(const short8*)&Qp_s[mtp * 16 + lm][32 + quad * 8];
#pragma unroll
            for (int n = 0; n < 3; n++) {
                int nt = ntp + n;
                short8 b0 = *(const short8*)&Kp_s[nt * 16 + lm][quad * 8];
                short8 b1 = *(const short8*)&Kp_s[nt * 16 + lm][32 + quad * 8];
                f32x4 acc = {0, 0, 0, 0};
                acc = __builtin_amdgcn_mfma_f32_16x16x32_bf16(a0, b0, acc, 0, 0, 0);
                acc = __builtin_amdgcn_mfma_f32_16x16x32_bf16(a1, b1, acc, 0, 0, 0);
#pragma unroll
                for (int r = 0; r < 4; r++)
                    Pt_s[mtp * 16 + quad * 4 + r][nt * 16 + lm] = acc[r];
            }
        }
        __syncthreads();   // B: scores in LDS

        // ---- online softmax (8 threads / row) ----
        float p[8];
        {
            float mx = NEG_INF;
#pragma unroll
            for (int j = 0; j < 8; j++) {
                int col = sc + j;
                float s = (Sc_s[sr][col] + Pt_s[sr][col - sr + 31]) * 0.125f;
                if (k0 + col > q0 + sr) s = NEG_INF;
                p[j] = s;
                mx = fmaxf(mx, s);
            }
            mx = fmaxf(mx, __shfl_xor(mx, 1, 8));
            mx = fmaxf(mx, __shfl_xor(mx, 2, 8));
            mx = fmaxf(mx, __shfl_xor(mx, 4, 8));
            float mnew = fmaxf(m_run, mx);
            float alpha = __expf(m_run - mnew);
            float ls = 0.0f;
#pragma unroll
            for (int j = 0; j < 8; j++) { p[j] = __expf(p[j] - mnew); ls += p[j]; }
            ls += __shfl_xor(ls, 1, 8);
            ls += __shfl_xor(ls, 2, 8);
            ls += __shfl_xor(ls, 4, 8);
            l_run = l_run * alpha + ls;
            m_run = mnew;
            if ((t & 7) == 0) arow_s[sr] = alpha;
        }
        __syncthreads();   // C: all Sc_s reads done; alpha ready

        {
            short8 pv;
#pragma unroll
            for (int j = 0; j < 8; j++) { bf16 x = (bf16)p[j]; pv[j] = *(short*)&x; }
            *(short8*)&Pb[sr * 72 + sc] = pv;
        }
        __syncthreads();   // D: P bf16 ready

        // ---- O update: acc = alpha*acc + P V ----
        {
            float al[4];
#pragma unroll
            for (int r = 0; r < 4; r++) al[r] = arow_s[mtc * 16 + quad * 4 + r];
            short8 a0 = *(const short8*)&Pb[(mtc * 16 + lm) * 72 + quad * 8];
            short8 a1 = *(const short8*)&Pb[(mtc * 16 + lm) * 72 + 32 + quad * 8];
#pragma unroll
            for (int n = 0; n < 2; n++) {
                int nt = ntc + n;
#pragma unroll
                for (int r = 0; r < 4; r++) accO[n][r] *= al[r];
                short8 b0, b1;
#pragma unroll
                for (int j = 0; j < 8; j++) {
                    bf16 x0 = V_s[quad * 8 + j][nt * 16 + lm];
                    bf16 x1 = V_s[32 + quad * 8 + j][nt * 16 + lm];
                    b0[j] = *(short*)&x0;
                    b1[j] = *(short*)&x1;
                }
                accO[n] = __builtin_amdgcn_mfma_f32_16x16x32_bf16(a0, b0, accO[n], 0, 0, 0);
                accO[n] = __builtin_amdgcn_mfma_f32_16x16x32_bf16(a1, b1, accO[n], 0, 0, 0);
            }
        }
        __syncthreads();   // E: protect V_s/Pb/arow before next staging
    }

    if ((t & 7) == 0) arow_s[sr] = l_run;
    __syncthreads();

    float linv[4];
#pragma unroll
    for (int r = 0; r < 4; r++) linv[r] = 1.0f / arow_s[mtc * 16 + quad * 4 + r];
#pragma unroll
    for (int n = 0; n < 2; n++) {
        int nt = ntc + n;
#pragma unroll
        for (int r = 0; r < 4; r++) {
            int row = mtc * 16 + quad * 4 + r;
            ao[(((size_t)(q0 + row) * BATCH + b) * EMB) + h * HD + nt * 16 + lm] =
                (bf16)(accO[n][r] * linv[r]);
        }
    }
}

// ---------------------------------------------------------------------------
extern "C" void kernel_launch(void* const* d_in, const int* in_sizes, int n_in,
                              void* d_out, int out_size, void* d_ws, size_t ws_size,
                              hipStream_t stream)
{
    const void* query = d_in[0];
    const void* key   = d_in[1];
    const void* value = d_in[2];
    const void* pe    = d_in[3];
    const void* w_q   = d_in[4];
    const void* w_k   = d_in[5];
    const void* w_v   = d_in[6];
    const void* w_kp  = d_in[7];
    const void* w_out = d_in[8];
    const void* cb    = d_in[9];
    const void* pb    = d_in[10];
    float* out = (float*)d_out;

    bf16* qc = (bf16*)d_ws;
    bf16* qp = qc + (size_t)4194304;
    bf16* kw = qp + (size_t)4194304;
    bf16* vw = kw + (size_t)4194304;
    bf16* kp = vw + (size_t)4194304;
    bf16* ao = kp + (size_t)4194304;

    dim3 blk(256);
    gemm_bt<0><<<dim3(64, 16), blk, 0, stream>>>(query, w_q, qc, qp, nullptr, cb, pb, QL * BATCH, 0);
    gemm_bt<1><<<dim3(64, 16), blk, 0, stream>>>(key,   w_k, kw, nullptr, nullptr, nullptr, nullptr, KLEN * BATCH, 0);
    gemm_bt<1><<<dim3(64, 16), blk, 0, stream>>>(value, w_v, vw, nullptr, nullptr, nullptr, nullptr, KLEN * BATCH, 0);
    gemm_bt<2><<<dim3(64, 16), blk, 0, stream>>>(pe, w_kp, kp, nullptr, nullptr, nullptr, nullptr, SPE, EMB);

    attn_mfma<<<dim3(QL / 32, NH, BATCH), blk, 0, stream>>>(qc, qp, kw, vw, kp, ao);

    gemm_bt<3><<<dim3(64, 16), blk, 0, stream>>>(ao, w_out, nullptr, nullptr, out, nullptr, nullptr, QL * BATCH, 0);
}

// Round 5
// 609.677 us; speedup vs baseline: 5.7167x; 2.7902x over previous
//
#include <hip/hip_runtime.h>
#include <hip/hip_bf16.h>

typedef __hip_bfloat16 bf16;
typedef __attribute__((ext_vector_type(8))) short short8;
typedef __attribute__((ext_vector_type(4))) float f32x4;
typedef __attribute__((ext_vector_type(4))) unsigned int u32x4;

#define QL   2048
#define KLEN 2048
#define BATCH 2
#define EMB  1024
#define NH   16
#define HD   64
#define SPE  4095   // 2*KLEN - 1 pe rows (slice starts at pe row 1)

// ---------------------------------------------------------------------------
// input dtype handling (inputs are f32; detection keeps us safe either way)
// ---------------------------------------------------------------------------
__device__ __forceinline__ float ldf(const void* __restrict__ p, size_t i, int f32) {
    return f32 ? ((const float*)p)[i] : __bfloat162float(((const bf16*)p)[i]);
}

__device__ int detect_f32(const void* __restrict__ p) {
    const unsigned short* u = (const unsigned short*)p;
    int bad = 0;
    for (int i = 0; i < 256; i++) {
        int e = (u[i] >> 7) & 0xFF;
        if (e >= 0x8A) bad++;   // |x| >= 2048, or NaN/Inf
    }
    return bad >= 8;
}

// f32 -> bf16 conversion, vectorized 4/thread. Elements >= zeroFrom write 0.
__global__ __launch_bounds__(256) void conv_one(
    const void* __restrict__ src, bf16* __restrict__ dst,
    long n4, long srcOffEl, long zeroFromEl)
{
    __shared__ int f32s;
    if (threadIdx.x == 0) f32s = detect_f32(src);
    __syncthreads();
    const int f32 = f32s;
    const long stride = (long)gridDim.x * blockDim.x;
    for (long i = (long)blockIdx.x * blockDim.x + threadIdx.x; i < n4; i += stride) {
        long e = i * 4;
        ushort4 o;
        if (e >= zeroFromEl) {
            o.x = o.y = o.z = o.w = 0;
        } else if (f32) {
            float4 v = ((const float4*)src)[(srcOffEl >> 2) + i];
            bf16 a = (bf16)v.x, b = (bf16)v.y, c = (bf16)v.z, d = (bf16)v.w;
            o.x = *(unsigned short*)&a; o.y = *(unsigned short*)&b;
            o.z = *(unsigned short*)&c; o.w = *(unsigned short*)&d;
        } else {
            o = ((const ushort4*)src)[(srcOffEl >> 2) + i];
        }
        ((ushort4*)dst)[i] = o;
    }
}

// ---------------------------------------------------------------------------
// MFMA GEMM: C[4096,1024] = A[4096,1024] @ W[1024,1024]^T (both bf16 ws),
// fp32 accum. Tile 128(M)x64(N), BK=32, global_load_lds(16B) staging with
// XOR chunk swizzle (chunk' = chunk ^ ((row>>1)&3)) for conflict-light
// ds_read_b128 fragment reads.
// MODE 0: -> qc/qp (+biases), [B][H][QL][HD]
// MODE 1: -> [B][H][KLEN][HD]
// MODE 2: -> [H][SPE][HD] (Mwrite=4095)
// MODE 3: -> f32 row-major d_out
// ---------------------------------------------------------------------------
__device__ __forceinline__ void llds16(const bf16* g, bf16* l) {
    __builtin_amdgcn_global_load_lds(
        (const __attribute__((address_space(1))) void*)g,
        (__attribute__((address_space(3))) void*)l,
        16, 0, 0);
}

template<int MODE>
__global__ __launch_bounds__(256) void gemm_mfma(
    const bf16* __restrict__ A, const bf16* __restrict__ W,
    bf16* __restrict__ out0, bf16* __restrict__ out1, float* __restrict__ outf,
    const bf16* __restrict__ bias0, const bf16* __restrict__ bias1, int Mwrite)
{
    __shared__ __align__(16) bf16 Asd[128 * 32];
    __shared__ __align__(16) bf16 Wsd[64 * 32];

    const int t = threadIdx.x;
    const int w = t >> 6, lane = t & 63, lm = lane & 15, quad = lane >> 4;
    const int m0 = blockIdx.x * 128, n0 = blockIdx.y * 64;
    const int wm = (w & 1) * 64, wn = (w >> 1) * 32;
    const int rswz = (quad ^ ((lm >> 1) & 3)) * 8;   // swizzled chunk offset

    f32x4 acc[4][2] = {};

    for (int k0 = 0; k0 < 1024; k0 += 32) {
        // ---- stage A (128x32) : 2 chunks/thread ----
#pragma unroll
        for (int i = 0; i < 2; i++) {
            int c = i * 256 + t;
            int r = c >> 2;
            int gc = (c & 3) ^ ((r >> 1) & 3);
            llds16(A + (size_t)(m0 + r) * 1024 + k0 + gc * 8,
                   Asd + (size_t)(c & ~63) * 8);
        }
        // ---- stage W (64x32) : 1 chunk/thread ----
        {
            int c = t;
            int r = c >> 2;
            int gc = (c & 3) ^ ((r >> 1) & 3);
            llds16(W + (size_t)(n0 + r) * 1024 + k0 + gc * 8,
                   Wsd + (size_t)(c & ~63) * 8);
        }
        __syncthreads();

        short8 wf[2];
#pragma unroll
        for (int nt = 0; nt < 2; nt++)
            wf[nt] = *(const short8*)&Wsd[(wn + nt * 16 + lm) * 32 + rswz];
#pragma unroll
        for (int mt = 0; mt < 4; mt++) {
            short8 af = *(const short8*)&Asd[(wm + mt * 16 + lm) * 32 + rswz];
#pragma unroll
            for (int nt = 0; nt < 2; nt++)
                acc[mt][nt] = __builtin_amdgcn_mfma_f32_16x16x32_bf16(af, wf[nt], acc[mt][nt], 0, 0, 0);
        }
        __syncthreads();
    }

    // ---- epilogue ----
#pragma unroll
    for (int mt = 0; mt < 4; mt++) {
#pragma unroll
        for (int nt = 0; nt < 2; nt++) {
#pragma unroll
            for (int r4 = 0; r4 < 4; r4++) {
                int row = m0 + wm + mt * 16 + quad * 4 + r4;
                int col = n0 + wn + nt * 16 + lm;
                if (row >= Mwrite) continue;
                float v = acc[mt][nt][r4];
                if constexpr (MODE == 0) {
                    int l = row >> 1, b = row & 1;
                    int h = col >> 6, d = col & 63;
                    size_t idx = ((size_t)(b * NH + h) * QL + l) * HD + d;
                    out0[idx] = (bf16)(v + __bfloat162float(bias0[col]));
                    out1[idx] = (bf16)(v + __bfloat162float(bias1[col]));
                } else if constexpr (MODE == 1) {
                    int l = row >> 1, b = row & 1;
                    int h = col >> 6, d = col & 63;
                    size_t idx = ((size_t)(b * NH + h) * KLEN + l) * HD + d;
                    out0[idx] = (bf16)v;
                } else if constexpr (MODE == 2) {
                    int h = col >> 6, d = col & 63;
                    size_t idx = ((size_t)h * SPE + row) * HD + d;
                    out0[idx] = (bf16)v;
                } else {
                    outf[(size_t)row * 1024 + col] = v;
                }
            }
        }
    }
}

// ---------------------------------------------------------------------------
// MFMA flash attention with TXL relative positions (unchanged, passing).
// ---------------------------------------------------------------------------
#define NEG_INF (-1.0e30f)

__global__ __launch_bounds__(256) void attn_mfma(
    const bf16* __restrict__ qc_g, const bf16* __restrict__ qp_g,
    const bf16* __restrict__ k_g,  const bf16* __restrict__ v_g,
    const bf16* __restrict__ kpos_g, bf16* __restrict__ ao)
{
    const int bx = blockIdx.x;
    const int h  = blockIdx.y;
    const int b  = blockIdx.z;
    const int q0 = bx * 32;

    const bf16* qc_bh  = qc_g + ((size_t)(b * NH + h) * QL) * HD;
    const bf16* qp_bh  = qp_g + ((size_t)(b * NH + h) * QL) * HD;
    const bf16* k_bh   = k_g  + ((size_t)(b * NH + h) * KLEN) * HD;
    const bf16* v_bh   = v_g  + ((size_t)(b * NH + h) * KLEN) * HD;
    const bf16* kpos_h = kpos_g + (size_t)h * SPE * HD;

    __shared__ __align__(16) bf16 Qc_s[32][72];
    __shared__ __align__(16) bf16 Qp_s[32][72];
    __shared__ __align__(16) bf16 K_s [64][72];
    __shared__ __align__(16) bf16 V_s [64][66];
    __shared__ __align__(16) bf16 Kp_s[96][72];
    __shared__ __align__(16) float Sc_s[32][65];
    __shared__ __align__(16) float Pt_s[32][97];
    __shared__ float arow_s[32];
    bf16* Pb = (bf16*)&Sc_s[0][0];   // [32][72] bf16 alias (after sync)

    const int t = threadIdx.x;
    const int w = t >> 6, lane = t & 63, lm = lane & 15, quad = lane >> 4;

    {
        int row = t >> 3, ch = (t & 7) * 8;
        *(u32x4*)&Qc_s[row][ch] = *(const u32x4*)&qc_bh[(size_t)(q0 + row) * HD + ch];
        *(u32x4*)&Qp_s[row][ch] = *(const u32x4*)&qp_bh[(size_t)(q0 + row) * HD + ch];
    }

    const int sr = t >> 3;
    const int sc = (t & 7) * 8;
    float m_run = NEG_INF, l_run = 0.0f;

    const int mtc = w & 1;
    const int ntc = (w >> 1) * 2;
    const int mtp = w >> 1;
    const int ntp = (w & 1) * 3;

    f32x4 accO[2] = {{0,0,0,0},{0,0,0,0}};

    const int nkt = (bx >> 1) + 1;
    for (int kt = 0; kt < nkt; kt++) {
        const int k0 = kt * 64;
        const int s0 = k0 - q0 + 2016;

#pragma unroll
        for (int i = 0; i < 2; i++) {
            int idx = i * 256 + t, row = idx >> 3, ch = (idx & 7) * 8;
            *(u32x4*)&K_s[row][ch] = *(const u32x4*)&k_bh[(size_t)(k0 + row) * HD + ch];
        }
#pragma unroll
        for (int i = 0; i < 8; i++) {
            int idx = i * 256 + t, row = idx >> 5, c2 = idx & 31;
            *(unsigned int*)&V_s[row][c2 * 2] =
                *(const unsigned int*)&v_bh[(size_t)(k0 + row) * HD + c2 * 2];
        }
#pragma unroll
        for (int i = 0; i < 3; i++) {
            int idx = i * 256 + t, row = idx >> 3, ch = (idx & 7) * 8;
            *(u32x4*)&Kp_s[row][ch] = *(const u32x4*)&kpos_h[(size_t)(s0 + row) * HD + ch];
        }
        __syncthreads();

        {
            short8 a0 = *(const short8*)&Qc_s[mtc * 16 + lm][quad * 8];
            short8 a1 = *(const short8*)&Qc_s[mtc * 16 + lm][32 + quad * 8];
#pragma unroll
            for (int n = 0; n < 2; n++) {
                int nt = ntc + n;
                short8 b0 = *(const short8*)&K_s[nt * 16 + lm][quad * 8];
                short8 b1 = *(const short8*)&K_s[nt * 16 + lm][32 + quad * 8];
                f32x4 acc = {0, 0, 0, 0};
                acc = __builtin_amdgcn_mfma_f32_16x16x32_bf16(a0, b0, acc, 0, 0, 0);
                acc = __builtin_amdgcn_mfma_f32_16x16x32_bf16(a1, b1, acc, 0, 0, 0);
#pragma unroll
                for (int r = 0; r < 4; r++)
                    Sc_s[mtc * 16 + quad * 4 + r][nt * 16 + lm] = acc[r];
            }
        }
        {
            short8 a0 = *(const short8*)&Qp_s[mtp * 16 + lm][quad * 8];
            short8 a1 = *(const short8*)&Qp_s[mtp * 16 + lm][32 + quad * 8];
#pragma unroll
            for (int n = 0; n < 3; n++) {
                int nt = ntp + n;
                short8 b0 = *(const short8*)&Kp_s[nt * 16 + lm][quad * 8];
                short8 b1 = *(const short8*)&Kp_s[nt * 16 + lm][32 + quad * 8];
                f32x4 acc = {0, 0, 0, 0};
                acc = __builtin_amdgcn_mfma_f32_16x16x32_bf16(a0, b0, acc, 0, 0, 0);
                acc = __builtin_amdgcn_mfma_f32_16x16x32_bf16(a1, b1, acc, 0, 0, 0);
#pragma unroll
                for (int r = 0; r < 4; r++)
                    Pt_s[mtp * 16 + quad * 4 + r][nt * 16 + lm] = acc[r];
            }
        }
        __syncthreads();

        float p[8];
        {
            float mx = NEG_INF;
#pragma unroll
            for (int j = 0; j < 8; j++) {
                int col = sc + j;
                float s = (Sc_s[sr][col] + Pt_s[sr][col - sr + 31]) * 0.125f;
                if (k0 + col > q0 + sr) s = NEG_INF;
                p[j] = s;
                mx = fmaxf(mx, s);
            }
            mx = fmaxf(mx, __shfl_xor(mx, 1, 8));
            mx = fmaxf(mx, __shfl_xor(mx, 2, 8));
            mx = fmaxf(mx, __shfl_xor(mx, 4, 8));
            float mnew = fmaxf(m_run, mx);
            float alpha = __expf(m_run - mnew);
            float ls = 0.0f;
#pragma unroll
            for (int j = 0; j < 8; j++) { p[j] = __expf(p[j] - mnew); ls += p[j]; }
            ls += __shfl_xor(ls, 1, 8);
            ls += __shfl_xor(ls, 2, 8);
            ls += __shfl_xor(ls, 4, 8);
            l_run = l_run * alpha + ls;
            m_run = mnew;
            if ((t & 7) == 0) arow_s[sr] = alpha;
        }
        __syncthreads();

        {
            short8 pv;
#pragma unroll
            for (int j = 0; j < 8; j++) { bf16 x = (bf16)p[j]; pv[j] = *(short*)&x; }
            *(short8*)&Pb[sr * 72 + sc] = pv;
        }
        __syncthreads();

        {
            float al[4];
#pragma unroll
            for (int r = 0; r < 4; r++) al[r] = arow_s[mtc * 16 + quad * 4 + r];
            short8 a0 = *(const short8*)&Pb[(mtc * 16 + lm) * 72 + quad * 8];
            short8 a1 = *(const short8*)&Pb[(mtc * 16 + lm) * 72 + 32 + quad * 8];
#pragma unroll
            for (int n = 0; n < 2; n++) {
                int nt = ntc + n;
#pragma unroll
                for (int r = 0; r < 4; r++) accO[n][r] *= al[r];
                short8 b0, b1;
#pragma unroll
                for (int j = 0; j < 8; j++) {
                    bf16 x0 = V_s[quad * 8 + j][nt * 16 + lm];
                    bf16 x1 = V_s[32 + quad * 8 + j][nt * 16 + lm];
                    b0[j] = *(short*)&x0;
                    b1[j] = *(short*)&x1;
                }
                accO[n] = __builtin_amdgcn_mfma_f32_16x16x32_bf16(a0, b0, accO[n], 0, 0, 0);
                accO[n] = __builtin_amdgcn_mfma_f32_16x16x32_bf16(a1, b1, accO[n], 0, 0, 0);
            }
        }
        __syncthreads();
    }

    if ((t & 7) == 0) arow_s[sr] = l_run;
    __syncthreads();

    float linv[4];
#pragma unroll
    for (int r = 0; r < 4; r++) linv[r] = 1.0f / arow_s[mtc * 16 + quad * 4 + r];
#pragma unroll
    for (int n = 0; n < 2; n++) {
        int nt = ntc + n;
#pragma unroll
        for (int r = 0; r < 4; r++) {
            int row = mtc * 16 + quad * 4 + r;
            ao[(((size_t)(q0 + row) * BATCH + b) * EMB) + h * HD + nt * 16 + lm] =
                (bf16)(accO[n][r] * linv[r]);
        }
    }
}

// ---------------------------------------------------------------------------
extern "C" void kernel_launch(void* const* d_in, const int* in_sizes, int n_in,
                              void* d_out, int out_size, void* d_ws, size_t ws_size,
                              hipStream_t stream)
{
    const void* query = d_in[0];
    const void* key   = d_in[1];
    const void* value = d_in[2];
    const void* pe    = d_in[3];
    const void* w_q   = d_in[4];
    const void* w_k   = d_in[5];
    const void* w_v   = d_in[6];
    const void* w_kp  = d_in[7];
    const void* w_out = d_in[8];
    const void* cb    = d_in[9];
    const void* pb    = d_in[10];
    float* out = (float*)d_out;

    const size_t SLAB = 4194304;
    bf16* qc   = (bf16*)d_ws;          // S0
    bf16* qp   = qc + SLAB;            // S1
    bf16* kw   = qp + SLAB;            // S2
    bf16* vw   = kw + SLAB;            // S3
    bf16* kpos = vw + SLAB;            // S4
    bf16* ao   = kpos + SLAB;          // S5
    bf16* stg  = ao + SLAB;            // S6 (A-input staging, reused)
    bf16* wqb  = stg + SLAB;           // S7: wq,wk,wv,wkp
    bf16* wkb  = wqb + 1048576;
    bf16* wvb  = wkb + 1048576;
    bf16* wkpb = wvb + 1048576;
    bf16* wob  = wkpb + 1048576;       // S8: wo, cb, pb
    bf16* cbb  = wob + 1048576;
    bf16* pbb  = cbb + 1024;

    dim3 blk(256);
    const long BIGN4 = 1048576;        // 4194304/4
    const long WN4   = 262144;         // 1048576/4

    // weights & biases -> bf16
    conv_one<<<dim3(1024), blk, 0, stream>>>(w_q,  wqb,  WN4, 0, 1L<<40);
    conv_one<<<dim3(1024), blk, 0, stream>>>(w_k,  wkb,  WN4, 0, 1L<<40);
    conv_one<<<dim3(1024), blk, 0, stream>>>(w_v,  wvb,  WN4, 0, 1L<<40);
    conv_one<<<dim3(1024), blk, 0, stream>>>(w_kp, wkpb, WN4, 0, 1L<<40);
    conv_one<<<dim3(1024), blk, 0, stream>>>(w_out, wob, WN4, 0, 1L<<40);
    conv_one<<<dim3(1),    blk, 0, stream>>>(cb, cbb, 256, 0, 1L<<40);
    conv_one<<<dim3(1),    blk, 0, stream>>>(pb, pbb, 256, 0, 1L<<40);

    dim3 ggrid(32, 16);
    // q proj
    conv_one<<<dim3(1024), blk, 0, stream>>>(query, stg, BIGN4, 0, 1L<<40);
    gemm_mfma<0><<<ggrid, blk, 0, stream>>>(stg, wqb, qc, qp, nullptr, cbb, pbb, 4096);
    // k proj
    conv_one<<<dim3(1024), blk, 0, stream>>>(key, stg, BIGN4, 0, 1L<<40);
    gemm_mfma<1><<<ggrid, blk, 0, stream>>>(stg, wkb, kw, nullptr, nullptr, nullptr, nullptr, 4096);
    // v proj
    conv_one<<<dim3(1024), blk, 0, stream>>>(value, stg, BIGN4, 0, 1L<<40);
    gemm_mfma<1><<<ggrid, blk, 0, stream>>>(stg, wvb, vw, nullptr, nullptr, nullptr, nullptr, 4096);
    // pe proj (skip row 0; zero-pad row 4095)
    conv_one<<<dim3(1024), blk, 0, stream>>>(pe, stg, BIGN4, 1024, 4193280);
    gemm_mfma<2><<<ggrid, blk, 0, stream>>>(stg, wkpb, kpos, nullptr, nullptr, nullptr, nullptr, 4095);

    // attention
    attn_mfma<<<dim3(QL / 32, NH, BATCH), blk, 0, stream>>>(qc, qp, kw, vw, kpos, ao);

    // output projection (f32 out)
    gemm_mfma<3><<<ggrid, blk, 0, stream>>>(ao, wob, nullptr, nullptr, out, nullptr, nullptr, 4096);
}

// Round 6
// 450.363 us; speedup vs baseline: 7.7389x; 1.3537x over previous
//
#include <hip/hip_runtime.h>
#include <hip/hip_bf16.h>

typedef __hip_bfloat16 bf16;
typedef __attribute__((ext_vector_type(8))) short short8;
typedef __attribute__((ext_vector_type(8))) unsigned short u16x8;
typedef __attribute__((ext_vector_type(4))) float f32x4;

#define QL   2048
#define KLEN 2048
#define BATCH 2
#define EMB  1024
#define NH   16
#define HD   64
#define SPE  4095   // 2*KLEN - 1 pe rows (slice starts at pe row 1)

// ---------------------------------------------------------------------------
__device__ int detect_f32(const void* __restrict__ p) {
    const unsigned short* u = (const unsigned short*)p;
    int bad = 0;
    for (int i = 0; i < 256; i++) {
        int e = (u[i] >> 7) & 0xFF;
        if (e >= 0x8A) bad++;   // |x| >= 2048, or NaN/Inf
    }
    return bad >= 8;
}

__device__ __forceinline__ ushort4 cvt4(const void* src, long u4i, int f32) {
    ushort4 o;
    if (f32) {
        float4 v = ((const float4*)src)[u4i];
        bf16 a = (bf16)v.x, b = (bf16)v.y, c = (bf16)v.z, e = (bf16)v.w;
        o.x = *(unsigned short*)&a; o.y = *(unsigned short*)&b;
        o.z = *(unsigned short*)&c; o.w = *(unsigned short*)&e;
    } else {
        o = ((const ushort4*)src)[u4i];
    }
    return o;
}

// fused weight/bias conversion: 5 x 1M weights + cb + pb -> dst slab
__global__ __launch_bounds__(256) void conv_w(
    const void* w0, const void* w1, const void* w2, const void* w3, const void* w4,
    const void* cb, const void* pb, bf16* __restrict__ dst)
{
    const int t = threadIdx.x;
    const int bid = blockIdx.x;
    __shared__ int f32s;
    if (bid < 1280) {
        const int seg = bid >> 8, inner = bid & 255;
        const void* src = seg == 0 ? w0 : seg == 1 ? w1 : seg == 2 ? w2 : seg == 3 ? w3 : w4;
        bf16* d = dst + (size_t)seg * 1048576;
        if (t == 0) f32s = detect_f32(src);
        __syncthreads();
        const int f32 = f32s;
#pragma unroll
        for (int i = 0; i < 4; i++) {
            long u4i = (long)inner * 1024 + i * 256 + t;
            ((ushort4*)d)[u4i] = cvt4(src, u4i, f32);
        }
    } else {
        if (t == 0) f32s = detect_f32(cb);
        __syncthreads();
        const int f32 = f32s;
        ((ushort4*)(dst + 5242880))[t]        = cvt4(cb, t, f32);
        ((ushort4*)(dst + 5242880 + 1024))[t] = cvt4(pb, t, f32);
    }
}

// fused activation conversion: query/key/value/pe -> 4 bf16 slabs
__global__ __launch_bounds__(256) void conv_act(
    const void* q, const void* k, const void* v, const void* pe,
    bf16* __restrict__ dq, bf16* __restrict__ dk,
    bf16* __restrict__ dv, bf16* __restrict__ dp)
{
    const int t = threadIdx.x;
    const int seg = blockIdx.x >> 10, inner = blockIdx.x & 1023;
    const void* src = seg == 0 ? q : seg == 1 ? k : seg == 2 ? v : pe;
    bf16* d = seg == 0 ? dq : seg == 1 ? dk : seg == 2 ? dv : dp;
    const long srcOff4 = (seg == 3) ? 256 : 0;          // pe: skip row 0 (1024 el)
    const long zero4   = (seg == 3) ? 1048320 : (1L << 40); // pe: zero row 4095
    __shared__ int f32s;
    if (t == 0) f32s = detect_f32(src);
    __syncthreads();
    const int f32 = f32s;
#pragma unroll
    for (int i = 0; i < 4; i++) {
        long u4i = (long)inner * 1024 + i * 256 + t;
        ushort4 o;
        if (u4i >= zero4) { o.x = o.y = o.z = o.w = 0; }
        else o = cvt4(src, srcOff4 + u4i, f32);
        ((ushort4*)d)[u4i] = o;
    }
}

// ---------------------------------------------------------------------------
__device__ __forceinline__ void llds16(const bf16* g, bf16* l) {
    __builtin_amdgcn_global_load_lds(
        (const __attribute__((address_space(1))) void*)g,
        (__attribute__((address_space(3))) void*)l,
        16, 0, 0);
}

// MFMA GEMM (unchanged from round 4, passing): C = A @ W^T, 128x64 tiles, BK=32
template<int MODE>
__global__ __launch_bounds__(256) void gemm_mfma(
    const bf16* __restrict__ A, const bf16* __restrict__ W,
    bf16* __restrict__ out0, bf16* __restrict__ out1, float* __restrict__ outf,
    const bf16* __restrict__ bias0, const bf16* __restrict__ bias1, int Mwrite)
{
    __shared__ __align__(16) bf16 Asd[128 * 32];
    __shared__ __align__(16) bf16 Wsd[64 * 32];

    const int t = threadIdx.x;
    const int w = t >> 6, lane = t & 63, lm = lane & 15, quad = lane >> 4;
    const int m0 = blockIdx.x * 128, n0 = blockIdx.y * 64;
    const int wm = (w & 1) * 64, wn = (w >> 1) * 32;
    const int rswz = (quad ^ ((lm >> 1) & 3)) * 8;

    f32x4 acc[4][2] = {};

    for (int k0 = 0; k0 < 1024; k0 += 32) {
#pragma unroll
        for (int i = 0; i < 2; i++) {
            int c = i * 256 + t;
            int r = c >> 2;
            int gc = (c & 3) ^ ((r >> 1) & 3);
            llds16(A + (size_t)(m0 + r) * 1024 + k0 + gc * 8,
                   Asd + (size_t)(c & ~63) * 8);
        }
        {
            int c = t;
            int r = c >> 2;
            int gc = (c & 3) ^ ((r >> 1) & 3);
            llds16(W + (size_t)(n0 + r) * 1024 + k0 + gc * 8,
                   Wsd + (size_t)(c & ~63) * 8);
        }
        __syncthreads();

        short8 wf[2];
#pragma unroll
        for (int nt = 0; nt < 2; nt++)
            wf[nt] = *(const short8*)&Wsd[(wn + nt * 16 + lm) * 32 + rswz];
#pragma unroll
        for (int mt = 0; mt < 4; mt++) {
            short8 af = *(const short8*)&Asd[(wm + mt * 16 + lm) * 32 + rswz];
#pragma unroll
            for (int nt = 0; nt < 2; nt++)
                acc[mt][nt] = __builtin_amdgcn_mfma_f32_16x16x32_bf16(af, wf[nt], acc[mt][nt], 0, 0, 0);
        }
        __syncthreads();
    }

#pragma unroll
    for (int mt = 0; mt < 4; mt++) {
#pragma unroll
        for (int nt = 0; nt < 2; nt++) {
#pragma unroll
            for (int r4 = 0; r4 < 4; r4++) {
                int row = m0 + wm + mt * 16 + quad * 4 + r4;
                int col = n0 + wn + nt * 16 + lm;
                if (row >= Mwrite) continue;
                float v = acc[mt][nt][r4];
                if constexpr (MODE == 0) {
                    int l = row >> 1, b = row & 1;
                    int h = col >> 6, d = col & 63;
                    size_t idx = ((size_t)(b * NH + h) * QL + l) * HD + d;
                    out0[idx] = (bf16)(v + __bfloat162float(bias0[col]));
                    out1[idx] = (bf16)(v + __bfloat162float(bias1[col]));
                } else if constexpr (MODE == 1) {
                    int l = row >> 1, b = row & 1;
                    int h = col >> 6, d = col & 63;
                    size_t idx = ((size_t)(b * NH + h) * KLEN + l) * HD + d;
                    out0[idx] = (bf16)v;
                } else if constexpr (MODE == 2) {
                    int h = col >> 6, d = col & 63;
                    size_t idx = ((size_t)h * SPE + row) * HD + d;
                    out0[idx] = (bf16)v;
                } else {
                    outf[(size_t)row * 1024 + col] = v;
                }
            }
        }
    }
}

// ---------------------------------------------------------------------------
// MFMA flash attention v2: 3 barriers/iter, async DMA staging, V transposed
// with swizzle, V double-buffered, heavy-first block order.
// ---------------------------------------------------------------------------
#define NEG_INF (-1.0e30f)

__global__ __launch_bounds__(256) void attn_mfma(
    const bf16* __restrict__ qc_g, const bf16* __restrict__ qp_g,
    const bf16* __restrict__ k_g,  const bf16* __restrict__ v_g,
    const bf16* __restrict__ kpos_g, bf16* __restrict__ ao)
{
    const int bx = 63 - blockIdx.x;     // heavy blocks dispatched first
    const int q0 = bx * 32;
    const int h  = blockIdx.y;
    const int b  = blockIdx.z;

    const bf16* qc_bh  = qc_g + ((size_t)(b * NH + h) * QL) * HD;
    const bf16* qp_bh  = qp_g + ((size_t)(b * NH + h) * QL) * HD;
    const bf16* k_bh   = k_g  + ((size_t)(b * NH + h) * KLEN) * HD;
    const bf16* v_bh   = v_g  + ((size_t)(b * NH + h) * KLEN) * HD;
    const bf16* kpos_h = kpos_g + (size_t)h * SPE * HD;

    __shared__ __align__(16) bf16 Qc_s[32 * 64];     // row-chunk swizzle ch^(r&7)
    __shared__ __align__(16) bf16 Qp_s[32 * 64];
    __shared__ __align__(16) bf16 K_s [64 * 64];
    __shared__ __align__(16) bf16 Kp_s[96 * 64];
    __shared__ __align__(16) bf16 Vt_s[2][64 * 64];  // [d][k], slot = kchunk^(d>>3)
    __shared__ __align__(16) bf16 Pb_s[32 * 64];     // row-chunk swizzle
    __shared__ float Sc_s[32][68];
    __shared__ float Pt_s[32][99];
    __shared__ float arow_s[32];

    const int t = threadIdx.x;
    const int w = t >> 6, lane = t & 63, lm = lane & 15, quad = lane >> 4;

    const int sr = t >> 3;            // softmax row
    const int sc = (t & 7) * 8;       // softmax col chunk
    const int vrr = t >> 3, vch = t & 7;   // V staging: k-pair 2*vrr, d-chunk vch
    const int vslot = ((vrr >> 2) ^ vch);

    const int mtc = w & 1;            // content/PV m-tile
    const int ntc = (w >> 1) * 2;     // content/PV n-tile base
    const int mtp = w >> 1;           // pos m-tile
    const int ntp = (w & 1) * 3;      // pos n-tile base

    float m_run = NEG_INF, l_run = 0.0f;
    f32x4 accO[2] = {{0,0,0,0},{0,0,0,0}};
    u16x8 vv0, vv1;

    const int nkt = (bx >> 1) + 1;

    // ---- prologue: stage Q + tile 0 ----
    {
        int r = t >> 3, ch = t & 7, gc = ch ^ (r & 7);
        llds16(qc_bh + (size_t)(q0 + r) * HD + gc * 8, Qc_s + (t & ~63) * 8);
        llds16(qp_bh + (size_t)(q0 + r) * HD + gc * 8, Qp_s + (t & ~63) * 8);
    }
#pragma unroll
    for (int i = 0; i < 2; i++) {
        int c = i * 256 + t, r = c >> 3, ch = c & 7, gc = ch ^ (r & 7);
        llds16(k_bh + (size_t)r * HD + gc * 8, K_s + (c & ~63) * 8);
    }
    {
        const int s0 = 2016 - q0;
#pragma unroll
        for (int i = 0; i < 3; i++) {
            int c = i * 256 + t, r = c >> 3, ch = c & 7, gc = ch ^ (r & 7);
            llds16(kpos_h + (size_t)(s0 + r) * HD + gc * 8, Kp_s + (c & ~63) * 8);
        }
    }
    vv0 = *(const u16x8*)&v_bh[(size_t)(2 * vrr)     * HD + vch * 8];
    vv1 = *(const u16x8*)&v_bh[(size_t)(2 * vrr + 1) * HD + vch * 8];

    for (int kt = 0; kt < nkt; kt++) {
        const int k0 = kt * 64;
        const int buf = kt & 1;

        // ---- transpose-write V for this tile (u32 pairs, 2-way free) ----
        {
            const int off = (2 * vrr) & 7;
#pragma unroll
            for (int j = 0; j < 8; j++) {
                unsigned int pair = (unsigned int)vv0[j] | ((unsigned int)vv1[j] << 16);
                *(unsigned int*)&Vt_s[buf][(vch * 8 + j) * 64 + vslot * 8 + off] = pair;
            }
        }
        __syncthreads();   // A: DMA staging + Vt writes visible

        // ---- content scores S = Qc K^T ----
        {
            int rowA = mtc * 16 + lm;
            short8 a0 = *(const short8*)&Qc_s[rowA * 64 + ((quad)     ^ (rowA & 7)) * 8];
            short8 a1 = *(const short8*)&Qc_s[rowA * 64 + ((4 + quad) ^ (rowA & 7)) * 8];
#pragma unroll
            for (int n = 0; n < 2; n++) {
                int rowB = (ntc + n) * 16 + lm;
                short8 b0 = *(const short8*)&K_s[rowB * 64 + ((quad)     ^ (rowB & 7)) * 8];
                short8 b1 = *(const short8*)&K_s[rowB * 64 + ((4 + quad) ^ (rowB & 7)) * 8];
                f32x4 acc = {0, 0, 0, 0};
                acc = __builtin_amdgcn_mfma_f32_16x16x32_bf16(a0, b0, acc, 0, 0, 0);
                acc = __builtin_amdgcn_mfma_f32_16x16x32_bf16(a1, b1, acc, 0, 0, 0);
#pragma unroll
                for (int r = 0; r < 4; r++)
                    Sc_s[mtc * 16 + quad * 4 + r][(ntc + n) * 16 + lm] = acc[r];
            }
        }
        // ---- pos band P~ = Qp Kp^T ----
        {
            int rowA = mtp * 16 + lm;
            short8 a0 = *(const short8*)&Qp_s[rowA * 64 + ((quad)     ^ (rowA & 7)) * 8];
            short8 a1 = *(const short8*)&Qp_s[rowA * 64 + ((4 + quad) ^ (rowA & 7)) * 8];
#pragma unroll
            for (int n = 0; n < 3; n++) {
                int rowB = (ntp + n) * 16 + lm;
                short8 b0 = *(const short8*)&Kp_s[rowB * 64 + ((quad)     ^ (rowB & 7)) * 8];
                short8 b1 = *(const short8*)&Kp_s[rowB * 64 + ((4 + quad) ^ (rowB & 7)) * 8];
                f32x4 acc = {0, 0, 0, 0};
                acc = __builtin_amdgcn_mfma_f32_16x16x32_bf16(a0, b0, acc, 0, 0, 0);
                acc = __builtin_amdgcn_mfma_f32_16x16x32_bf16(a1, b1, acc, 0, 0, 0);
#pragma unroll
                for (int r = 0; r < 4; r++)
                    Pt_s[mtp * 16 + quad * 4 + r][(ntp + n) * 16 + lm] = acc[r];
            }
        }
        __syncthreads();   // B: scores in LDS

        // ---- online softmax (8 threads / row) + P write ----
        {
            float p[8];
            float mx = NEG_INF;
#pragma unroll
            for (int j = 0; j < 8; j++) {
                int col = sc + j;
                float s = (Sc_s[sr][col] + Pt_s[sr][col - sr + 31]) * 0.125f;
                if (k0 + col > q0 + sr) s = NEG_INF;
                p[j] = s;
                mx = fmaxf(mx, s);
            }
            mx = fmaxf(mx, __shfl_xor(mx, 1, 8));
            mx = fmaxf(mx, __shfl_xor(mx, 2, 8));
            mx = fmaxf(mx, __shfl_xor(mx, 4, 8));
            float mnew = fmaxf(m_run, mx);
            float alpha = __expf(m_run - mnew);
            float ls = 0.0f;
#pragma unroll
            for (int j = 0; j < 8; j++) { p[j] = __expf(p[j] - mnew); ls += p[j]; }
            ls += __shfl_xor(ls, 1, 8);
            ls += __shfl_xor(ls, 2, 8);
            ls += __shfl_xor(ls, 4, 8);
            l_run = l_run * alpha + ls;
            m_run = mnew;
            if ((t & 7) == 0) arow_s[sr] = alpha;
            short8 pv;
#pragma unroll
            for (int j = 0; j < 8; j++) { bf16 x = (bf16)p[j]; pv[j] = *(short*)&x; }
            *(short8*)&Pb_s[sr * 64 + ((t & 7) ^ (sr & 7)) * 8] = pv;
        }
        __syncthreads();   // C: P + alpha ready; Sc/Pt/K/Kp reads done

        // ---- prefetch tile kt+1 (DMA overlaps PV + next softmax window) ----
        if (kt + 1 < nkt) {
            const int k0n = k0 + 64;
            const int s0n = k0n - q0 + 2016;
#pragma unroll
            for (int i = 0; i < 2; i++) {
                int c = i * 256 + t, r = c >> 3, ch = c & 7, gc = ch ^ (r & 7);
                llds16(k_bh + (size_t)(k0n + r) * HD + gc * 8, K_s + (c & ~63) * 8);
            }
#pragma unroll
            for (int i = 0; i < 3; i++) {
                int c = i * 256 + t, r = c >> 3, ch = c & 7, gc = ch ^ (r & 7);
                llds16(kpos_h + (size_t)(s0n + r) * HD + gc * 8, Kp_s + (c & ~63) * 8);
            }
            vv0 = *(const u16x8*)&v_bh[(size_t)(k0n + 2 * vrr)     * HD + vch * 8];
            vv1 = *(const u16x8*)&v_bh[(size_t)(k0n + 2 * vrr + 1) * HD + vch * 8];
        }

        // ---- O update: acc = alpha*acc + P V ----
        {
            float al[4];
#pragma unroll
            for (int r = 0; r < 4; r++) al[r] = arow_s[mtc * 16 + quad * 4 + r];
            int rowA = mtc * 16 + lm;
            short8 a0 = *(const short8*)&Pb_s[rowA * 64 + ((quad)     ^ (rowA & 7)) * 8];
            short8 a1 = *(const short8*)&Pb_s[rowA * 64 + ((4 + quad) ^ (rowA & 7)) * 8];
#pragma unroll
            for (int n = 0; n < 2; n++) {
                int d = (ntc + n) * 16 + lm;
                int dc = d >> 3;
                short8 b0 = *(const short8*)&Vt_s[buf][d * 64 + ((quad)     ^ dc) * 8];
                short8 b1 = *(const short8*)&Vt_s[buf][d * 64 + ((4 + quad) ^ dc) * 8];
#pragma unroll
                for (int r = 0; r < 4; r++) accO[n][r] *= al[r];
                accO[n] = __builtin_amdgcn_mfma_f32_16x16x32_bf16(a0, b0, accO[n], 0, 0, 0);
                accO[n] = __builtin_amdgcn_mfma_f32_16x16x32_bf16(a1, b1, accO[n], 0, 0, 0);
            }
        }
    }

    __syncthreads();                       // protect arow before l broadcast
    if ((t & 7) == 0) arow_s[sr] = l_run;
    __syncthreads();

    float linv[4];
#pragma unroll
    for (int r = 0; r < 4; r++) linv[r] = 1.0f / arow_s[mtc * 16 + quad * 4 + r];
#pragma unroll
    for (int n = 0; n < 2; n++) {
#pragma unroll
        for (int r = 0; r < 4; r++) {
            int row = mtc * 16 + quad * 4 + r;
            ao[(((size_t)(q0 + row) * BATCH + b) * EMB) + h * HD + (ntc + n) * 16 + lm] =
                (bf16)(accO[n][r] * linv[r]);
        }
    }
}

// ---------------------------------------------------------------------------
extern "C" void kernel_launch(void* const* d_in, const int* in_sizes, int n_in,
                              void* d_out, int out_size, void* d_ws, size_t ws_size,
                              hipStream_t stream)
{
    const void* query = d_in[0];
    const void* key   = d_in[1];
    const void* value = d_in[2];
    const void* pe    = d_in[3];
    const void* w_q   = d_in[4];
    const void* w_k   = d_in[5];
    const void* w_v   = d_in[6];
    const void* w_kp  = d_in[7];
    const void* w_out = d_in[8];
    const void* cb    = d_in[9];
    const void* pb    = d_in[10];
    float* out = (float*)d_out;

    const size_t SLAB = 4194304;
    bf16* qc   = (bf16*)d_ws;          // S0
    bf16* qp   = qc + SLAB;            // S1
    bf16* kw   = qp + SLAB;            // S2
    bf16* vw   = kw + SLAB;            // S3
    bf16* kpos = vw + SLAB;            // S4 (also value-staging before step 6)
    bf16* ao   = kpos + SLAB;          // S5 (also pe-staging before attention)
    bf16* stg  = ao + SLAB;            // S6 (key staging)
    bf16* wqb  = stg + SLAB;           // S7: wq,wk,wv,wkp,wo,cb,pb
    bf16* wkb  = wqb + 1048576;
    bf16* wvb  = wkb + 1048576;
    bf16* wkpb = wvb + 1048576;
    bf16* wob  = wkpb + 1048576;
    bf16* cbb  = wob + 1048576;
    bf16* pbb  = cbb + 1024;

    bf16* stgQ = (bf16*)d_out;         // query staging in d_out (overwritten at end)

    dim3 blk(256);

    conv_w<<<dim3(1281), blk, 0, stream>>>(w_q, w_k, w_v, w_kp, w_out, cb, pb, wqb);
    conv_act<<<dim3(4096), blk, 0, stream>>>(query, key, value, pe, stgQ, stg, kpos, ao);

    dim3 ggrid(32, 16);
    gemm_mfma<0><<<ggrid, blk, 0, stream>>>(stgQ, wqb, qc, qp, nullptr, cbb, pbb, 4096);
    gemm_mfma<1><<<ggrid, blk, 0, stream>>>(stg, wkb, kw, nullptr, nullptr, nullptr, nullptr, 4096);
    gemm_mfma<1><<<ggrid, blk, 0, stream>>>(kpos, wvb, vw, nullptr, nullptr, nullptr, nullptr, 4096);
    gemm_mfma<2><<<ggrid, blk, 0, stream>>>(ao, wkpb, kpos, nullptr, nullptr, nullptr, nullptr, 4095);

    attn_mfma<<<dim3(64, NH, BATCH), blk, 0, stream>>>(qc, qp, kw, vw, kpos, ao);

    gemm_mfma<3><<<ggrid, blk, 0, stream>>>(ao, wob, nullptr, nullptr, out, nullptr, nullptr, 4096);
}